// Round 10
// baseline (586.678 us; speedup 1.0000x reference)
//
#include <hip/hip_runtime.h>

// Problem constants (z: [4, 64, 32, 32, 32] f32, embedding: [1024, 64] f32)
#define CH     64
#define KC     1024
#define SP     32768              // 32*32*32
#define NBATCH 4
#define NTOK   (NBATCH * SP)      // 131072
#define MTOK   128                // tokens per block (32 per wave; round-1/2 verified fragments)
#define SZZ    68                 // zl row stride (floats)
#define ECH    128                // codes per LDS chunk (8 chunks, round-8 verified)
#define NCHK   (KC / ECH)         // 8
#define SZEB   72                 // ebl row stride in shorts (144 B = 9*16, b128-aligned)
#define CAP    8                  // candidate slots per token (overflow -> frozen full scan)
#define MARGIN 3.0f               // > 2*eps, eps = max |d_bf16 - d_fp32| (~0.9)

// d_out flat layout (all float32): z_q, loss, perplexity, indices, mean(dist)
#define OFF_ZQ   0
#define OFF_LOSS (NBATCH * CH * SP)      // 8388608
#define OFF_PERP (OFF_LOSS + 1)
#define OFF_IDX  (OFF_PERP + 1)          // 8388610
#define OFF_MEAN (OFF_IDX + NTOK)        // 8519682

// workspace layout (32-bit words)
// [0,1024)      int   hist
// [1024]        float sum_z2
// [1025]        float sum_e2
// [1026,1090)   float sum_zc[64]
// [1090,1154)   float sum_ec[64]
// [1154,2178)   float enorm[1024]
// [4096,20480)  ushort eb[1024*64]  (bf16 embedding table, 128 KB)

typedef __attribute__((ext_vector_type(8))) short  s16x8;   // 8 bf16 (4 VGPRs)
typedef __attribute__((ext_vector_type(4))) float  f32x4;

__device__ __forceinline__ unsigned short f2bf(float f) {   // RNE, deterministic
    unsigned int u = __float_as_uint(f);
    return (unsigned short)((u + 0x7fffu + ((u >> 16) & 1u)) >> 16);
}

// frozen exact fp32 distance (bitwise identical to round 0: stride-4
// fmaf chains ascending j, combine nrm - 2*((a0+a1)+(a2+a3)))
__device__ __forceinline__ float exact_dist(const float* zrow,
                                            const float* __restrict__ emb,
                                            const float* enl, int c) {
    const float4* er = (const float4*)(emb + (size_t)c * CH);
    float a0 = 0.f, a1 = 0.f, a2 = 0.f, a3 = 0.f;
#pragma unroll
    for (int j = 0; j < 16; ++j) {
        float4 e4 = er[j];
        a0 = fmaf(zrow[4 * j + 0], e4.x, a0);
        a1 = fmaf(zrow[4 * j + 1], e4.y, a1);
        a2 = fmaf(zrow[4 * j + 2], e4.z, a2);
        a3 = fmaf(zrow[4 * j + 3], e4.w, a3);
    }
    return enl[c] - 2.f * ((a0 + a1) + (a2 + a3));
}

// prep: blocks 0-3 enorm, block 4 col-stats + zero sums, 5-8 zero hist,
// 9-12 fp32->bf16 embedding table. (unchanged)
__global__ __launch_bounds__(256) void prep(const float* __restrict__ e,
                                            int* __restrict__ hist,
                                            float* __restrict__ sums,
                                            float* __restrict__ sum_zc,
                                            float* __restrict__ sum_ec,
                                            float* __restrict__ enorm,
                                            unsigned short* __restrict__ eb) {
    const int tid = threadIdx.x;
    const int bk = blockIdx.x;
    if (bk < 4) {
        int k = bk * 256 + tid;
        const float4* row = (const float4*)(e + (size_t)k * CH);
        float n = 0.f;
#pragma unroll
        for (int j = 0; j < CH / 4; ++j) {
            float4 v = row[j];
            n += v.x * v.x + v.y * v.y + v.z * v.z + v.w * v.w;
        }
        enorm[k] = n;
    } else if (bk == 4) {
        if (tid == 0) sums[0] = 0.f;
        if (tid < 64) sum_zc[tid] = 0.f;
        __shared__ float ls1[256];
        __shared__ float r2[4];
        int c = tid & 63;
        int strip = tid >> 6;
        float s1 = 0.f, s2 = 0.f;
        for (int k = strip * 256; k < strip * 256 + 256; ++k) {
            float v = e[k * CH + c];
            s1 += v;
            s2 = fmaf(v, v, s2);
        }
        ls1[tid] = s1;
        for (int off = 32; off; off >>= 1) s2 += __shfl_down(s2, off);
        if ((tid & 63) == 0) r2[tid >> 6] = s2;
        __syncthreads();
        if (strip == 0) sum_ec[c] = ls1[c] + ls1[64 + c] + ls1[128 + c] + ls1[192 + c];
        if (tid == 0) sums[1] = r2[0] + r2[1] + r2[2] + r2[3];
    } else if (bk < 9) {
        hist[(bk - 5) * 256 + tid] = 0;
    } else {
        int base = (bk - 9) * 16384;
        for (int j = 0; j < 64; ++j) {
            int i = base + tid + j * 256;
            eb[i] = f2bf(e[i]);
        }
    }
}

// A-fragment builder (round-1 verified): 8 bf16 from zrow channels base..base+7
#define MK8(A, ptr)                                            \
    {                                                          \
        float4 _a = *(const float4*)(ptr);                     \
        float4 _b = *(const float4*)((ptr) + 4);               \
        A[0] = (short)f2bf(_a.x); A[1] = (short)f2bf(_a.y);    \
        A[2] = (short)f2bf(_a.z); A[3] = (short)f2bf(_a.w);    \
        A[4] = (short)f2bf(_b.x); A[5] = (short)f2bf(_b.y);    \
        A[6] = (short)f2bf(_b.z); A[7] = (short)f2bf(_b.w);    \
    }

// main: round-8 structure with MTOK 64->128 (32 tokens/wave, 2 accumulator
// sets sharing each B read — round-1/2 verified inner loop). Halves per-token
// staging phases and B ds_reads chip-wide; MFMA total unchanged. Threshold is
// wave-local after the butterfly (round-1/2 verified) -> no dmin_l, no extra
// barrier. CAP 16->8 for the 64 KB LDS budget. LDS = 64512 B -> 2 blocks/CU.
__global__ __launch_bounds__(256, 2) void vq_main(const float* __restrict__ z,
                                                  const float* __restrict__ emb,
                                                  const unsigned short* __restrict__ eb,
                                                  const float* __restrict__ enorm,
                                                  float* __restrict__ out,
                                                  int* __restrict__ hist,
                                                  float* __restrict__ sums,
                                                  float* __restrict__ sum_zc) {
    __shared__ float zl[MTOK * SZZ];          // 34816 B fp32 z, token-major
    __shared__ unsigned short ebl[ECH * SZEB];// 18432 B bf16 e chunk, padded rows
    __shared__ float enorm_l[KC];             // 4096 B
    __shared__ float zs1[256], zs2[256];      // 2048 B z-stats scratch
    __shared__ int   cand[MTOK][CAP];         // 4096 B
    __shared__ int   ccnt[MTOK];              // 512 B
    __shared__ int   fi[MTOK];                // 512 B

    const int tid = threadIdx.x;
    const int w = tid >> 6;             // wave 0..3
    const int lane = tid & 63;
    const int n15 = lane & 15;
    const int q = lane >> 4;            // 0..3
    const int t0 = blockIdx.x * MTOK;   // grid = 1024
    const int bb = t0 >> 15;
    const int s0 = t0 & (SP - 1);

    // ---- stage z tile token-major (round-1 verified) + enorm + ccnt ----
    {
        const float* zbase = z + ((size_t)bb * CH) * SP + s0;
#pragma unroll
        for (int rep = 0; rep < 8; ++rep) {
            int idx = tid + rep * 256;      // 0..2047
            int c = idx >> 5;
            int tq = idx & 31;
            float4 v = *(const float4*)(zbase + (size_t)c * SP + tq * 4);
            zl[(4 * tq + 0) * SZZ + c] = v.x;
            zl[(4 * tq + 1) * SZZ + c] = v.y;
            zl[(4 * tq + 2) * SZZ + c] = v.z;
            zl[(4 * tq + 3) * SZZ + c] = v.w;
        }
#pragma unroll
        for (int j = 0; j < 4; ++j) enorm_l[tid + j * 256] = enorm[tid + j * 256];
        if (tid < MTOK) ccnt[tid] = 0;
    }
    __syncthreads();

    // ---- persistent A fragments: 2 groups of 16 tokens per wave (round-1) ----
    s16x8 A0, A1, A2, A3;
    {
        const float* zr0 = &zl[(w * 32 + n15) * SZZ];
        const float* zr1 = zr0 + 16 * SZZ;
        MK8(A0, zr0 + q * 8)
        MK8(A1, zr0 + 32 + q * 8)
        MK8(A2, zr1 + q * 8)
        MK8(A3, zr1 + 32 + q * 8)
    }
    const unsigned short* ebq = ebl + (size_t)n15 * SZEB + q * 8;

    // ---- pass 1: per-token min of d_bf (values only), chunked B in LDS ----
    float bmin0[4] = {3.4e38f, 3.4e38f, 3.4e38f, 3.4e38f};
    float bmin1[4] = {3.4e38f, 3.4e38f, 3.4e38f, 3.4e38f};
    for (int ch = 0; ch < NCHK; ++ch) {
        __syncthreads();   // prior chunk's ebl reads done
        // stage chunk ch (round-8 verified): row = i>>3, j = i&7
#pragma unroll
        for (int rep = 0; rep < ECH * 8 / 256; ++rep) {
            int i = tid + rep * 256;         // 0..ECH*8-1
            int row = i >> 3, j = i & 7;
            ((float4*)&ebl[row * SZEB])[j] =
                ((const float4*)(eb + (size_t)(ch * ECH + row) * CH))[j];
        }
        __syncthreads();
        for (int ct = 0; ct < ECH / 16; ++ct) {
            const unsigned short* p = ebq + ct * 16 * SZEB;
            s16x8 B0 = *(const s16x8*)p;
            s16x8 B1 = *(const s16x8*)(p + 32);
            float en = enorm_l[ch * ECH + ct * 16 + n15];
            f32x4 acc0 = {0.f, 0.f, 0.f, 0.f};
            f32x4 acc1 = {0.f, 0.f, 0.f, 0.f};
            acc0 = __builtin_amdgcn_mfma_f32_16x16x32_bf16(A0, B0, acc0, 0, 0, 0);
            acc0 = __builtin_amdgcn_mfma_f32_16x16x32_bf16(A1, B1, acc0, 0, 0, 0);
            acc1 = __builtin_amdgcn_mfma_f32_16x16x32_bf16(A2, B0, acc1, 0, 0, 0);
            acc1 = __builtin_amdgcn_mfma_f32_16x16x32_bf16(A3, B1, acc1, 0, 0, 0);
#pragma unroll
            for (int r = 0; r < 4; ++r) {
                bmin0[r] = fminf(bmin0[r], fmaf(-2.f, acc0[r], en));
                bmin1[r] = fminf(bmin1[r], fmaf(-2.f, acc1[r], en));
            }
        }
    }
    // butterfly over n15: min lands in all 16 lanes of the group (round-1/2
    // verified) -> threshold is wave-local, no LDS, no extra barrier
#pragma unroll
    for (int off = 1; off < 16; off <<= 1)
#pragma unroll
        for (int r = 0; r < 4; ++r) {
            bmin0[r] = fminf(bmin0[r], __shfl_xor(bmin0[r], off));
            bmin1[r] = fminf(bmin1[r], __shfl_xor(bmin1[r], off));
        }
    float thr0[4], thr1[4];
#pragma unroll
    for (int r = 0; r < 4; ++r) {
        thr0[r] = bmin0[r] + MARGIN;
        thr1[r] = bmin1[r] + MARGIN;
    }

    // ---- pass 2: identical compute, collect candidates within margin.
    //      chunk order 7,0..6: chunk 7 still resident -> no restage ----
    const int tb0 = w * 32 + 4 * q;      // group-0 tokens: tb0 + r
    const int tb1 = tb0 + 16;            // group-1 tokens
    for (int cc = 0; cc < NCHK; ++cc) {
        int ch = (cc == 0) ? (NCHK - 1) : (cc - 1);
        if (cc) {
            __syncthreads();
#pragma unroll
            for (int rep = 0; rep < ECH * 8 / 256; ++rep) {
                int i = tid + rep * 256;
                int row = i >> 3, j = i & 7;
                ((float4*)&ebl[row * SZEB])[j] =
                    ((const float4*)(eb + (size_t)(ch * ECH + row) * CH))[j];
            }
            __syncthreads();
        }
        for (int ct = 0; ct < ECH / 16; ++ct) {
            const unsigned short* p = ebq + ct * 16 * SZEB;
            s16x8 B0 = *(const s16x8*)p;
            s16x8 B1 = *(const s16x8*)(p + 32);
            float en = enorm_l[ch * ECH + ct * 16 + n15];
            f32x4 acc0 = {0.f, 0.f, 0.f, 0.f};
            f32x4 acc1 = {0.f, 0.f, 0.f, 0.f};
            acc0 = __builtin_amdgcn_mfma_f32_16x16x32_bf16(A0, B0, acc0, 0, 0, 0);
            acc0 = __builtin_amdgcn_mfma_f32_16x16x32_bf16(A1, B1, acc0, 0, 0, 0);
            acc1 = __builtin_amdgcn_mfma_f32_16x16x32_bf16(A2, B0, acc1, 0, 0, 0);
            acc1 = __builtin_amdgcn_mfma_f32_16x16x32_bf16(A3, B1, acc1, 0, 0, 0);
            int code = ch * ECH + ct * 16 + n15;
#pragma unroll
            for (int r = 0; r < 4; ++r) {
                float d0 = fmaf(-2.f, acc0[r], en);
                if (d0 <= thr0[r]) {
                    int pos = atomicAdd(&ccnt[tb0 + r], 1);
                    if (pos < CAP) cand[tb0 + r][pos] = code;
                }
                float d1 = fmaf(-2.f, acc1[r], en);
                if (d1 <= thr1[r]) {
                    int pos = atomicAdd(&ccnt[tb1 + r], 1);
                    if (pos < CAP) cand[tb1 + r][pos] = code;
                }
            }
        }
    }
    __syncthreads();

    // ---- exact fp32 rescore of candidates (frozen arithmetic) ----
    if (tid < MTOK) {
        int t = tid;
        const float* zrow = &zl[t * SZZ];
        int cnt = ccnt[t];
        float best = 3.4e38f;
        int bi = 0;
        if (cnt <= CAP) {
            for (int j = 0; j < cnt; ++j) {
                int c = cand[t][j];
                float d = exact_dist(zrow, emb, enorm_l, c);
                if (d < best || (d == best && c < bi)) { best = d; bi = c; }
            }
        } else {   // overflow fallback (rare): exact scan, ascending
            for (int c = 0; c < KC; ++c) {
                float d = exact_dist(zrow, emb, enorm_l, c);
                if (d < best) { best = d; bi = c; }
            }
        }
        fi[t] = bi;
        out[OFF_IDX + t0 + t] = (float)bi;   // coalesced
        atomicAdd(&hist[bi], 1);
    }
    __syncthreads();

    // ---- z_q epilogue: z + (e[code] - z), coalesced per channel (round-1) ----
#pragma unroll
    for (int rep = 0; rep < 32; ++rep) {
        int idx = tid + rep * 256;   // 0..8191
        int c = idx >> 7;
        int t = idx & 127;
        int code = fi[t];
        float ev = emb[(size_t)code * CH + c];   // L1/L2-hot gather
        float zv = zl[t * SZZ + c];
        out[OFF_ZQ + ((size_t)bb * CH + c) * SP + s0 + t] = zv + (ev - zv);
    }

    // ---- z statistics: two 64-token halves (round-1 verified structure) ----
#pragma unroll
    for (int h = 0; h < 2; ++h) {
        const int c = tid >> 2, qq = tid & 3;
        float s1 = 0.f, s2 = 0.f;
#pragma unroll
        for (int tt = 0; tt < 16; ++tt) {
            float v = zl[(h * 64 + qq * 16 + tt) * SZZ + c];
            s1 += v;
            s2 = fmaf(v, v, s2);
        }
        zs1[tid] = s1;
        zs2[tid] = s2;
        __syncthreads();
        if (tid < 64) {
            float a = zs1[4 * tid] + zs1[4 * tid + 1] + zs1[4 * tid + 2] + zs1[4 * tid + 3];
            atomicAdd(&sum_zc[tid], a);
            float bsum = zs2[4 * tid] + zs2[4 * tid + 1] + zs2[4 * tid + 2] + zs2[4 * tid + 3];
            for (int off = 32; off; off >>= 1) bsum += __shfl_down(bsum, off);
            if (tid == 0) atomicAdd(&sums[0], bsum);
        }
        __syncthreads();
    }
}

__global__ __launch_bounds__(1024) void finalize(const int* __restrict__ hist,
                                                 const float* __restrict__ sums,
                                                 const float* __restrict__ sum_zc,
                                                 const float* __restrict__ sum_ec,
                                                 float* __restrict__ out) {
    __shared__ float red[1024];
    int k = threadIdx.x;
    float p = (float)hist[k] * (1.0f / (float)NTOK);
    red[k] = p * logf(p + 1e-10f);
    __syncthreads();
    for (int off = 512; off; off >>= 1) {
        if (k < off) red[k] += red[k + off];
        __syncthreads();
    }
    if (k == 0) {
        out[OFF_PERP] = expf(-red[0]);
        out[OFF_LOSS] = 0.f;
        double dot = 0.0;
        for (int c = 0; c < CH; ++c) dot += (double)sum_zc[c] * (double)sum_ec[c];
        double mean = ((double)KC * (double)sums[0] + (double)NTOK * (double)sums[1] - 2.0 * dot)
                      / ((double)NTOK * (double)KC);
        out[OFF_MEAN] = (float)mean;
    }
}

extern "C" void kernel_launch(void* const* d_in, const int* in_sizes, int n_in,
                              void* d_out, int out_size, void* d_ws, size_t ws_size,
                              hipStream_t stream) {
    const float* z   = (const float*)d_in[0];
    const float* emb = (const float*)d_in[1];
    float* out = (float*)d_out;

    int*            hist   = (int*)d_ws;
    float*          sums   = (float*)d_ws + 1024;   // [0]=sum_z2 [1]=sum_e2
    float*          sum_zc = (float*)d_ws + 1026;
    float*          sum_ec = (float*)d_ws + 1090;
    float*          enorm  = (float*)d_ws + 1154;
    unsigned short* eb     = (unsigned short*)((int*)d_ws + 4096);  // 128 KB bf16 table

    prep<<<13, 256, 0, stream>>>(emb, hist, sums, sum_zc, sum_ec, enorm, eb);
    vq_main<<<NTOK / MTOK, 256, 0, stream>>>(z, emb, eb, enorm, out, hist, sums, sum_zc);
    finalize<<<1, 1024, 0, stream>>>(hist, sums, sum_zc, sum_ec, out);
}

// Round 11
// 233.484 us; speedup vs baseline: 2.5127x; 2.5127x over previous
//
#include <hip/hip_runtime.h>

// Problem constants (z: [4, 64, 32, 32, 32] f32, embedding: [1024, 64] f32)
#define CH     64
#define KC     1024
#define SP     32768              // 32*32*32
#define NBATCH 4
#define NTOK   (NBATCH * SP)      // 131072
#define MTOK   128                // tokens per block (32 per wave; R10-verified fragments)
#define SZZ    68                 // zl row stride (floats)
#define ECH    128                // codes per LDS chunk (8 chunks, round-8 verified)
#define NCHK   (KC / ECH)         // 8
#define SZEB   72                 // ebl row stride in shorts (144 B = 9*16, b128-aligned)
#define CAP    16                 // candidate slots per token — MUST be 16: margin sets are
                                  // often 9..16 codes; CAP<=8 routes tokens through the
                                  // serial full-scan fallback (+~400 us chip-wide, rounds 1-5,10)
#define MARGIN 3.0f               // > 2*eps, eps = max |d_bf16 - d_fp32| (~0.9)

// d_out flat layout (all float32): z_q, loss, perplexity, indices, mean(dist)
#define OFF_ZQ   0
#define OFF_LOSS (NBATCH * CH * SP)      // 8388608
#define OFF_PERP (OFF_LOSS + 1)
#define OFF_IDX  (OFF_PERP + 1)          // 8388610
#define OFF_MEAN (OFF_IDX + NTOK)        // 8519682

// workspace layout (32-bit words)
// [0,1024)      int   hist
// [1024]        float sum_z2
// [1025]        float sum_e2
// [1026,1090)   float sum_zc[64]
// [1090,1154)   float sum_ec[64]
// [1154,2178)   float enorm[1024]
// [4096,20480)  ushort eb[1024*64]  (bf16 embedding table, 128 KB)

typedef __attribute__((ext_vector_type(8))) short  s16x8;   // 8 bf16 (4 VGPRs)
typedef __attribute__((ext_vector_type(4))) float  f32x4;

__device__ __forceinline__ unsigned short f2bf(float f) {   // RNE, deterministic
    unsigned int u = __float_as_uint(f);
    return (unsigned short)((u + 0x7fffu + ((u >> 16) & 1u)) >> 16);
}

// frozen exact fp32 distance (bitwise identical to round 0: stride-4
// fmaf chains ascending j, combine nrm - 2*((a0+a1)+(a2+a3)))
__device__ __forceinline__ float exact_dist(const float* zrow,
                                            const float* __restrict__ emb,
                                            const float* __restrict__ enl, int c) {
    const float4* er = (const float4*)(emb + (size_t)c * CH);
    float a0 = 0.f, a1 = 0.f, a2 = 0.f, a3 = 0.f;
#pragma unroll
    for (int j = 0; j < 16; ++j) {
        float4 e4 = er[j];
        a0 = fmaf(zrow[4 * j + 0], e4.x, a0);
        a1 = fmaf(zrow[4 * j + 1], e4.y, a1);
        a2 = fmaf(zrow[4 * j + 2], e4.z, a2);
        a3 = fmaf(zrow[4 * j + 3], e4.w, a3);
    }
    return enl[c] - 2.f * ((a0 + a1) + (a2 + a3));
}

// prep: blocks 0-3 enorm, block 4 col-stats + zero sums, 5-8 zero hist,
// 9-12 fp32->bf16 embedding table. (unchanged)
__global__ __launch_bounds__(256) void prep(const float* __restrict__ e,
                                            int* __restrict__ hist,
                                            float* __restrict__ sums,
                                            float* __restrict__ sum_zc,
                                            float* __restrict__ sum_ec,
                                            float* __restrict__ enorm,
                                            unsigned short* __restrict__ eb) {
    const int tid = threadIdx.x;
    const int bk = blockIdx.x;
    if (bk < 4) {
        int k = bk * 256 + tid;
        const float4* row = (const float4*)(e + (size_t)k * CH);
        float n = 0.f;
#pragma unroll
        for (int j = 0; j < CH / 4; ++j) {
            float4 v = row[j];
            n += v.x * v.x + v.y * v.y + v.z * v.z + v.w * v.w;
        }
        enorm[k] = n;
    } else if (bk == 4) {
        if (tid == 0) sums[0] = 0.f;
        if (tid < 64) sum_zc[tid] = 0.f;
        __shared__ float ls1[256];
        __shared__ float r2[4];
        int c = tid & 63;
        int strip = tid >> 6;
        float s1 = 0.f, s2 = 0.f;
        for (int k = strip * 256; k < strip * 256 + 256; ++k) {
            float v = e[k * CH + c];
            s1 += v;
            s2 = fmaf(v, v, s2);
        }
        ls1[tid] = s1;
        for (int off = 32; off; off >>= 1) s2 += __shfl_down(s2, off);
        if ((tid & 63) == 0) r2[tid >> 6] = s2;
        __syncthreads();
        if (strip == 0) sum_ec[c] = ls1[c] + ls1[64 + c] + ls1[128 + c] + ls1[192 + c];
        if (tid == 0) sums[1] = r2[0] + r2[1] + r2[2] + r2[3];
    } else if (bk < 9) {
        hist[(bk - 5) * 256 + tid] = 0;
    } else {
        int base = (bk - 9) * 16384;
        for (int j = 0; j < 64; ++j) {
            int i = base + tid + j * 256;
            eb[i] = f2bf(e[i]);
        }
    }
}

// A-fragment builder (R10-verified): 8 bf16 from zrow channels base..base+7
#define MK8(A, ptr)                                            \
    {                                                          \
        float4 _a = *(const float4*)(ptr);                     \
        float4 _b = *(const float4*)((ptr) + 4);               \
        A[0] = (short)f2bf(_a.x); A[1] = (short)f2bf(_a.y);    \
        A[2] = (short)f2bf(_a.z); A[3] = (short)f2bf(_a.w);    \
        A[4] = (short)f2bf(_b.x); A[5] = (short)f2bf(_b.y);    \
        A[6] = (short)f2bf(_b.z); A[7] = (short)f2bf(_b.w);    \
    }

// main: R10 structure (MTOK=128, 32 tokens/wave, shared B reads) with the CAP
// poison removed (CAP=16, the R0/R8-verified capacity). LDS fit via chunk-local
// enl (R5-verified) + zs aliased onto dead cand (R5-verified). 62976 B -> 2/CU.
__global__ __launch_bounds__(256, 2) void vq_main(const float* __restrict__ z,
                                                  const float* __restrict__ emb,
                                                  const unsigned short* __restrict__ eb,
                                                  const float* __restrict__ enorm,
                                                  float* __restrict__ out,
                                                  int* __restrict__ hist,
                                                  float* __restrict__ sums,
                                                  float* __restrict__ sum_zc) {
    __shared__ float zl[MTOK * SZZ];          // 34816 B fp32 z, token-major
    __shared__ unsigned short ebl[ECH * SZEB];// 18432 B bf16 e chunk, padded rows
    __shared__ float enl[ECH];                // 512 B enorm chunk
    __shared__ int   cand[MTOK][CAP];         // 8192 B (zs-aliased at tail)
    __shared__ int   ccnt[MTOK];              // 512 B
    __shared__ int   fi[MTOK];                // 512 B

    const int tid = threadIdx.x;
    const int w = tid >> 6;             // wave 0..3
    const int lane = tid & 63;
    const int n15 = lane & 15;
    const int q = lane >> 4;            // 0..3
    const int t0 = blockIdx.x * MTOK;   // grid = 1024
    const int bb = t0 >> 15;
    const int s0 = t0 & (SP - 1);

    // ---- stage z tile token-major (R10-verified) + ccnt ----
    {
        const float* zbase = z + ((size_t)bb * CH) * SP + s0;
#pragma unroll
        for (int rep = 0; rep < 8; ++rep) {
            int idx = tid + rep * 256;      // 0..2047
            int c = idx >> 5;
            int tq = idx & 31;
            float4 v = *(const float4*)(zbase + (size_t)c * SP + tq * 4);
            zl[(4 * tq + 0) * SZZ + c] = v.x;
            zl[(4 * tq + 1) * SZZ + c] = v.y;
            zl[(4 * tq + 2) * SZZ + c] = v.z;
            zl[(4 * tq + 3) * SZZ + c] = v.w;
        }
        if (tid < MTOK) ccnt[tid] = 0;
    }
    __syncthreads();

    // ---- persistent A fragments: 2 groups of 16 tokens per wave (R10) ----
    s16x8 A0, A1, A2, A3;
    {
        const float* zr0 = &zl[(w * 32 + n15) * SZZ];
        const float* zr1 = zr0 + 16 * SZZ;
        MK8(A0, zr0 + q * 8)
        MK8(A1, zr0 + 32 + q * 8)
        MK8(A2, zr1 + q * 8)
        MK8(A3, zr1 + 32 + q * 8)
    }
    const unsigned short* ebq = ebl + (size_t)n15 * SZEB + q * 8;

    // ---- pass 1: per-token min of d_bf (values only), chunked B in LDS ----
    float bmin0[4] = {3.4e38f, 3.4e38f, 3.4e38f, 3.4e38f};
    float bmin1[4] = {3.4e38f, 3.4e38f, 3.4e38f, 3.4e38f};
    for (int ch = 0; ch < NCHK; ++ch) {
        __syncthreads();   // prior chunk's ebl/enl reads done
        // stage chunk ch (round-8 verified) + chunk-local enorm (R5 verified)
#pragma unroll
        for (int rep = 0; rep < ECH * 8 / 256; ++rep) {
            int i = tid + rep * 256;         // 0..ECH*8-1
            int row = i >> 3, j = i & 7;
            ((float4*)&ebl[row * SZEB])[j] =
                ((const float4*)(eb + (size_t)(ch * ECH + row) * CH))[j];
        }
        if (tid < ECH) enl[tid] = enorm[ch * ECH + tid];
        __syncthreads();
        for (int ct = 0; ct < ECH / 16; ++ct) {
            const unsigned short* p = ebq + ct * 16 * SZEB;
            s16x8 B0 = *(const s16x8*)p;
            s16x8 B1 = *(const s16x8*)(p + 32);
            float en = enl[ct * 16 + n15];
            f32x4 acc0 = {0.f, 0.f, 0.f, 0.f};
            f32x4 acc1 = {0.f, 0.f, 0.f, 0.f};
            acc0 = __builtin_amdgcn_mfma_f32_16x16x32_bf16(A0, B0, acc0, 0, 0, 0);
            acc0 = __builtin_amdgcn_mfma_f32_16x16x32_bf16(A1, B1, acc0, 0, 0, 0);
            acc1 = __builtin_amdgcn_mfma_f32_16x16x32_bf16(A2, B0, acc1, 0, 0, 0);
            acc1 = __builtin_amdgcn_mfma_f32_16x16x32_bf16(A3, B1, acc1, 0, 0, 0);
#pragma unroll
            for (int r = 0; r < 4; ++r) {
                bmin0[r] = fminf(bmin0[r], fmaf(-2.f, acc0[r], en));
                bmin1[r] = fminf(bmin1[r], fmaf(-2.f, acc1[r], en));
            }
        }
    }
    // butterfly over n15: min lands in all 16 lanes of the group (R10-verified)
    // -> threshold is wave-local, no LDS, no extra barrier
#pragma unroll
    for (int off = 1; off < 16; off <<= 1)
#pragma unroll
        for (int r = 0; r < 4; ++r) {
            bmin0[r] = fminf(bmin0[r], __shfl_xor(bmin0[r], off));
            bmin1[r] = fminf(bmin1[r], __shfl_xor(bmin1[r], off));
        }
    float thr0[4], thr1[4];
#pragma unroll
    for (int r = 0; r < 4; ++r) {
        thr0[r] = bmin0[r] + MARGIN;
        thr1[r] = bmin1[r] + MARGIN;
    }

    // ---- pass 2: identical compute, collect candidates within margin.
    //      chunk order 7,0..6: chunk 7 (ebl+enl) still resident -> no restage ----
    const int tb0 = w * 32 + 4 * q;      // group-0 tokens: tb0 + r
    const int tb1 = tb0 + 16;            // group-1 tokens
    for (int cc = 0; cc < NCHK; ++cc) {
        int ch = (cc == 0) ? (NCHK - 1) : (cc - 1);
        if (cc) {
            __syncthreads();
#pragma unroll
            for (int rep = 0; rep < ECH * 8 / 256; ++rep) {
                int i = tid + rep * 256;
                int row = i >> 3, j = i & 7;
                ((float4*)&ebl[row * SZEB])[j] =
                    ((const float4*)(eb + (size_t)(ch * ECH + row) * CH))[j];
            }
            if (tid < ECH) enl[tid] = enorm[ch * ECH + tid];
            __syncthreads();
        }
        for (int ct = 0; ct < ECH / 16; ++ct) {
            const unsigned short* p = ebq + ct * 16 * SZEB;
            s16x8 B0 = *(const s16x8*)p;
            s16x8 B1 = *(const s16x8*)(p + 32);
            float en = enl[ct * 16 + n15];
            f32x4 acc0 = {0.f, 0.f, 0.f, 0.f};
            f32x4 acc1 = {0.f, 0.f, 0.f, 0.f};
            acc0 = __builtin_amdgcn_mfma_f32_16x16x32_bf16(A0, B0, acc0, 0, 0, 0);
            acc0 = __builtin_amdgcn_mfma_f32_16x16x32_bf16(A1, B1, acc0, 0, 0, 0);
            acc1 = __builtin_amdgcn_mfma_f32_16x16x32_bf16(A2, B0, acc1, 0, 0, 0);
            acc1 = __builtin_amdgcn_mfma_f32_16x16x32_bf16(A3, B1, acc1, 0, 0, 0);
            int code = ch * ECH + ct * 16 + n15;
#pragma unroll
            for (int r = 0; r < 4; ++r) {
                float d0 = fmaf(-2.f, acc0[r], en);
                if (d0 <= thr0[r]) {
                    int pos = atomicAdd(&ccnt[tb0 + r], 1);
                    if (pos < CAP) cand[tb0 + r][pos] = code;
                }
                float d1 = fmaf(-2.f, acc1[r], en);
                if (d1 <= thr1[r]) {
                    int pos = atomicAdd(&ccnt[tb1 + r], 1);
                    if (pos < CAP) cand[tb1 + r][pos] = code;
                }
            }
        }
    }
    __syncthreads();

    // ---- exact fp32 rescore of candidates (frozen arithmetic; global enorm,
    //      R5-verified identical values) ----
    if (tid < MTOK) {
        int t = tid;
        const float* zrow = &zl[t * SZZ];
        int cnt = ccnt[t];
        float best = 3.4e38f;
        int bi = 0;
        if (cnt <= CAP) {
            for (int j = 0; j < cnt; ++j) {
                int c = cand[t][j];
                float d = exact_dist(zrow, emb, enorm, c);
                if (d < best || (d == best && c < bi)) { best = d; bi = c; }
            }
        } else {   // overflow fallback (rare at CAP=16): exact scan, ascending
            for (int c = 0; c < KC; ++c) {
                float d = exact_dist(zrow, emb, enorm, c);
                if (d < best) { best = d; bi = c; }
            }
        }
        fi[t] = bi;
        out[OFF_IDX + t0 + t] = (float)bi;   // coalesced
        atomicAdd(&hist[bi], 1);
    }
    __syncthreads();

    // ---- z_q epilogue: z + (e[code] - z), coalesced per channel (R10) ----
#pragma unroll
    for (int rep = 0; rep < 32; ++rep) {
        int idx = tid + rep * 256;   // 0..8191
        int c = idx >> 7;
        int t = idx & 127;
        int code = fi[t];
        float ev = emb[(size_t)code * CH + c];   // L1/L2-hot gather
        float zv = zl[t * SZZ + c];
        out[OFF_ZQ + ((size_t)bb * CH + c) * SP + s0 + t] = zv + (ev - zv);
    }

    // ---- z statistics: two 64-token halves (R10-verified structure; zs
    //      aliased onto dead cand, R5-verified) ----
    float* zs1 = reinterpret_cast<float*>(cand);   // 2048 B needed <= 8192 B
    float* zs2 = zs1 + 256;
#pragma unroll
    for (int h = 0; h < 2; ++h) {
        const int c = tid >> 2, qq = tid & 3;
        float s1 = 0.f, s2 = 0.f;
#pragma unroll
        for (int tt = 0; tt < 16; ++tt) {
            float v = zl[(h * 64 + qq * 16 + tt) * SZZ + c];
            s1 += v;
            s2 = fmaf(v, v, s2);
        }
        zs1[tid] = s1;
        zs2[tid] = s2;
        __syncthreads();
        if (tid < 64) {
            float a = zs1[4 * tid] + zs1[4 * tid + 1] + zs1[4 * tid + 2] + zs1[4 * tid + 3];
            atomicAdd(&sum_zc[tid], a);
            float bsum = zs2[4 * tid] + zs2[4 * tid + 1] + zs2[4 * tid + 2] + zs2[4 * tid + 3];
            for (int off = 32; off; off >>= 1) bsum += __shfl_down(bsum, off);
            if (tid == 0) atomicAdd(&sums[0], bsum);
        }
        __syncthreads();
    }
}

__global__ __launch_bounds__(1024) void finalize(const int* __restrict__ hist,
                                                 const float* __restrict__ sums,
                                                 const float* __restrict__ sum_zc,
                                                 const float* __restrict__ sum_ec,
                                                 float* __restrict__ out) {
    __shared__ float red[1024];
    int k = threadIdx.x;
    float p = (float)hist[k] * (1.0f / (float)NTOK);
    red[k] = p * logf(p + 1e-10f);
    __syncthreads();
    for (int off = 512; off; off >>= 1) {
        if (k < off) red[k] += red[k + off];
        __syncthreads();
    }
    if (k == 0) {
        out[OFF_PERP] = expf(-red[0]);
        out[OFF_LOSS] = 0.f;
        double dot = 0.0;
        for (int c = 0; c < CH; ++c) dot += (double)sum_zc[c] * (double)sum_ec[c];
        double mean = ((double)KC * (double)sums[0] + (double)NTOK * (double)sums[1] - 2.0 * dot)
                      / ((double)NTOK * (double)KC);
        out[OFF_MEAN] = (float)mean;
    }
}

extern "C" void kernel_launch(void* const* d_in, const int* in_sizes, int n_in,
                              void* d_out, int out_size, void* d_ws, size_t ws_size,
                              hipStream_t stream) {
    const float* z   = (const float*)d_in[0];
    const float* emb = (const float*)d_in[1];
    float* out = (float*)d_out;

    int*            hist   = (int*)d_ws;
    float*          sums   = (float*)d_ws + 1024;   // [0]=sum_z2 [1]=sum_e2
    float*          sum_zc = (float*)d_ws + 1026;
    float*          sum_ec = (float*)d_ws + 1090;
    float*          enorm  = (float*)d_ws + 1154;
    unsigned short* eb     = (unsigned short*)((int*)d_ws + 4096);  // 128 KB bf16 table

    prep<<<13, 256, 0, stream>>>(emb, hist, sums, sum_zc, sum_ec, enorm, eb);
    vq_main<<<NTOK / MTOK, 256, 0, stream>>>(z, emb, eb, enorm, out, hist, sums, sum_zc);
    finalize<<<1, 1024, 0, stream>>>(hist, sums, sum_zc, sum_ec, out);
}

// Round 12
// 211.566 us; speedup vs baseline: 2.7730x; 1.1036x over previous
//
#include <hip/hip_runtime.h>

// Problem constants (z: [4, 64, 32, 32, 32] f32, embedding: [1024, 64] f32)
#define CH     64
#define KC     1024
#define SP     32768              // 32*32*32
#define NBATCH 4
#define NTOK   (NBATCH * SP)      // 131072
#define MTOK   64                 // tokens per block (R8-verified; beats MTOK=128 via residency)
#define SZZ    68                 // zl row stride (floats)
#define ECH    128                // codes per LDS chunk (8 chunks, R8-verified)
#define NCHK   (KC / ECH)         // 8
#define SZEB   72                 // ebl row stride in shorts (144 B = 9*16, b128-aligned)
#define CAP    16                 // MUST be 16: margin sets are often 9..16 codes; CAP<=8
                                  // routes tokens through the serial full-scan fallback
                                  // (+~400 us chip-wide — rounds 1-5,10 poison, proven by R10/R11 A/B)
#define MARGIN 3.0f               // > 2*eps, eps = max |d_bf16 - d_fp32| (~0.9)

// d_out flat layout (all float32): z_q, loss, perplexity, indices, mean(dist)
#define OFF_ZQ   0
#define OFF_LOSS (NBATCH * CH * SP)      // 8388608
#define OFF_PERP (OFF_LOSS + 1)
#define OFF_IDX  (OFF_PERP + 1)          // 8388610
#define OFF_MEAN (OFF_IDX + NTOK)        // 8519682

// workspace layout (32-bit words)
// [0,1024)      int   hist
// [1024]        float sum_z2
// [1025]        float sum_e2
// [1026,1090)   float sum_zc[64]
// [1090,1154)   float sum_ec[64]
// [1154,2178)   float enorm[1024]
// [4096,20480)  ushort eb[1024*64]  (bf16 embedding table, 128 KB)

typedef __attribute__((ext_vector_type(8))) short  s16x8;   // 8 bf16 (4 VGPRs)
typedef __attribute__((ext_vector_type(4))) float  f32x4;

__device__ __forceinline__ unsigned short f2bf(float f) {   // RNE, deterministic
    unsigned int u = __float_as_uint(f);
    return (unsigned short)((u + 0x7fffu + ((u >> 16) & 1u)) >> 16);
}

// frozen exact fp32 distance (bitwise identical to round 0: stride-4
// fmaf chains ascending j, combine nrm - 2*((a0+a1)+(a2+a3)))
__device__ __forceinline__ float exact_dist(const float* zrow,
                                            const float* __restrict__ emb,
                                            const float* __restrict__ enl, int c) {
    const float4* er = (const float4*)(emb + (size_t)c * CH);
    float a0 = 0.f, a1 = 0.f, a2 = 0.f, a3 = 0.f;
#pragma unroll
    for (int j = 0; j < 16; ++j) {
        float4 e4 = er[j];
        a0 = fmaf(zrow[4 * j + 0], e4.x, a0);
        a1 = fmaf(zrow[4 * j + 1], e4.y, a1);
        a2 = fmaf(zrow[4 * j + 2], e4.z, a2);
        a3 = fmaf(zrow[4 * j + 3], e4.w, a3);
    }
    return enl[c] - 2.f * ((a0 + a1) + (a2 + a3));
}

// prep: blocks 0-3 enorm, block 4 col-stats + zero sums, 5-8 zero hist,
// 9-12 fp32->bf16 embedding table. (unchanged)
__global__ __launch_bounds__(256) void prep(const float* __restrict__ e,
                                            int* __restrict__ hist,
                                            float* __restrict__ sums,
                                            float* __restrict__ sum_zc,
                                            float* __restrict__ sum_ec,
                                            float* __restrict__ enorm,
                                            unsigned short* __restrict__ eb) {
    const int tid = threadIdx.x;
    const int bk = blockIdx.x;
    if (bk < 4) {
        int k = bk * 256 + tid;
        const float4* row = (const float4*)(e + (size_t)k * CH);
        float n = 0.f;
#pragma unroll
        for (int j = 0; j < CH / 4; ++j) {
            float4 v = row[j];
            n += v.x * v.x + v.y * v.y + v.z * v.z + v.w * v.w;
        }
        enorm[k] = n;
    } else if (bk == 4) {
        if (tid == 0) sums[0] = 0.f;
        if (tid < 64) sum_zc[tid] = 0.f;
        __shared__ float ls1[256];
        __shared__ float r2[4];
        int c = tid & 63;
        int strip = tid >> 6;
        float s1 = 0.f, s2 = 0.f;
        for (int k = strip * 256; k < strip * 256 + 256; ++k) {
            float v = e[k * CH + c];
            s1 += v;
            s2 = fmaf(v, v, s2);
        }
        ls1[tid] = s1;
        for (int off = 32; off; off >>= 1) s2 += __shfl_down(s2, off);
        if ((tid & 63) == 0) r2[tid >> 6] = s2;
        __syncthreads();
        if (strip == 0) sum_ec[c] = ls1[c] + ls1[64 + c] + ls1[128 + c] + ls1[192 + c];
        if (tid == 0) sums[1] = r2[0] + r2[1] + r2[2] + r2[3];
    } else if (bk < 9) {
        hist[(bk - 5) * 256 + tid] = 0;
    } else {
        int base = (bk - 9) * 16384;
        for (int j = 0; j < 64; ++j) {
            int i = base + tid + j * 256;
            eb[i] = f2bf(e[i]);
        }
    }
}

// main: R8 kernel (144.5 us anchor) + R11-verified LDS diet for 4 blocks/CU:
//  1) enorm_l[1024] -> chunk-local enl[128] inside the stage-barrier pair;
//     rescore reads global enorm (identical values, R11-verified)
//  2) dmin_l + its barrier removed: butterfly leaves min in all 16 lanes
//     (order-independent min, bitwise identical; R10/R11-verified)
//  3) zs stats scratch aliased onto dead cand (R11-verified)
// LDS 47104 -> 40960 B => 4 blocks/CU (was 3). All value arithmetic frozen.
__global__ __launch_bounds__(256, 2) void vq_main(const float* __restrict__ z,
                                                  const float* __restrict__ emb,
                                                  const unsigned short* __restrict__ eb,
                                                  const float* __restrict__ enorm,
                                                  float* __restrict__ out,
                                                  int* __restrict__ hist,
                                                  float* __restrict__ sums,
                                                  float* __restrict__ sum_zc) {
    __shared__ float zl[MTOK * SZZ];          // 17408 B fp32 z, token-major
    __shared__ unsigned short ebl[ECH * SZEB];// 18432 B bf16 e chunk, padded rows
    __shared__ float enl[ECH];                // 512 B enorm chunk
    __shared__ int   cand[MTOK][CAP];         // 4096 B (zs-aliased at tail)
    __shared__ int   ccnt[MTOK];              // 256 B
    __shared__ int   fi[MTOK];                // 256 B

    const int tid = threadIdx.x;
    const int w = tid >> 6;             // wave 0..3
    const int lane = tid & 63;
    const int n15 = lane & 15;
    const int q = lane >> 4;            // 0..3
    const int t0 = blockIdx.x * MTOK;   // grid = 2048
    const int bb = t0 >> 15;
    const int s0 = t0 & (SP - 1);

    // ---- stage z tile token-major + ccnt (R8 prologue minus enorm copy) ----
    {
        const float* zbase = z + ((size_t)bb * CH) * SP + s0;
#pragma unroll
        for (int j = 0; j < 4; ++j) {
            int idx = tid + j * 256;        // 0..1023
            int c = idx >> 4;
            int tq = idx & 15;
            float4 v = *(const float4*)(zbase + (size_t)c * SP + tq * 4);
            zl[(4 * tq + 0) * SZZ + c] = v.x;
            zl[(4 * tq + 1) * SZZ + c] = v.y;
            zl[(4 * tq + 2) * SZZ + c] = v.z;
            zl[(4 * tq + 3) * SZZ + c] = v.w;
        }
        if (tid < MTOK) ccnt[tid] = 0;
    }
    __syncthreads();

    // ---- build persistent A fragments (R8 layout, verified) ----
    s16x8 A0, A1;
    {
        const float* zrow = &zl[(w * 16 + n15) * SZZ];
        float4 za = *(const float4*)(zrow + q * 8);
        float4 zb = *(const float4*)(zrow + q * 8 + 4);
        float4 zc = *(const float4*)(zrow + 32 + q * 8);
        float4 zd = *(const float4*)(zrow + 32 + q * 8 + 4);
        A0[0] = (short)f2bf(za.x); A0[1] = (short)f2bf(za.y);
        A0[2] = (short)f2bf(za.z); A0[3] = (short)f2bf(za.w);
        A0[4] = (short)f2bf(zb.x); A0[5] = (short)f2bf(zb.y);
        A0[6] = (short)f2bf(zb.z); A0[7] = (short)f2bf(zb.w);
        A1[0] = (short)f2bf(zc.x); A1[1] = (short)f2bf(zc.y);
        A1[2] = (short)f2bf(zc.z); A1[3] = (short)f2bf(zc.w);
        A1[4] = (short)f2bf(zd.x); A1[5] = (short)f2bf(zd.y);
        A1[6] = (short)f2bf(zd.z); A1[7] = (short)f2bf(zd.w);
    }
    const unsigned short* ebq = ebl + (size_t)n15 * SZEB + q * 8;

    // ---- pass 1: per-token min of d_bf (values only), chunked B in LDS ----
    float bmin[4] = {3.4e38f, 3.4e38f, 3.4e38f, 3.4e38f};
    for (int ch = 0; ch < NCHK; ++ch) {
        __syncthreads();   // prior chunk's ebl/enl reads done
        // stage chunk ch (R8-verified) + chunk-local enorm (R11-verified)
#pragma unroll
        for (int rep = 0; rep < ECH * 8 / 256; ++rep) {
            int i = tid + rep * 256;         // 0..ECH*8-1
            int row = i >> 3, j = i & 7;
            ((float4*)&ebl[row * SZEB])[j] =
                ((const float4*)(eb + (size_t)(ch * ECH + row) * CH))[j];
        }
        if (tid < ECH) enl[tid] = enorm[ch * ECH + tid];
        __syncthreads();
        for (int ct = 0; ct < ECH / 16; ++ct) {
            const unsigned short* p = ebq + ct * 16 * SZEB;
            s16x8 B0 = *(const s16x8*)p;
            s16x8 B1 = *(const s16x8*)(p + 32);
            f32x4 acc = {0.f, 0.f, 0.f, 0.f};
            acc = __builtin_amdgcn_mfma_f32_16x16x32_bf16(A0, B0, acc, 0, 0, 0);
            acc = __builtin_amdgcn_mfma_f32_16x16x32_bf16(A1, B1, acc, 0, 0, 0);
            float en = enl[ct * 16 + n15];
#pragma unroll
            for (int r = 0; r < 4; ++r) {
                float d = fmaf(-2.f, acc[r], en);
                bmin[r] = fminf(bmin[r], d);
            }
        }
    }
    // butterfly over n15: min lands in all 16 lanes (order-independent min,
    // R10/R11-verified) -> threshold wave-local, no dmin_l, no extra barrier
#pragma unroll
    for (int off = 1; off < 16; off <<= 1)
#pragma unroll
        for (int r = 0; r < 4; ++r)
            bmin[r] = fminf(bmin[r], __shfl_xor(bmin[r], off));
    float thr[4];
#pragma unroll
    for (int r = 0; r < 4; ++r) thr[r] = bmin[r] + MARGIN;

    // ---- pass 2: identical compute, collect candidates within margin.
    //      chunk order 7,0..6: chunk 7 (ebl+enl) still resident -> no restage ----
    for (int cc = 0; cc < NCHK; ++cc) {
        int ch = (cc == 0) ? (NCHK - 1) : (cc - 1);
        if (cc) {
            __syncthreads();
#pragma unroll
            for (int rep = 0; rep < ECH * 8 / 256; ++rep) {
                int i = tid + rep * 256;
                int row = i >> 3, j = i & 7;
                ((float4*)&ebl[row * SZEB])[j] =
                    ((const float4*)(eb + (size_t)(ch * ECH + row) * CH))[j];
            }
            if (tid < ECH) enl[tid] = enorm[ch * ECH + tid];
            __syncthreads();
        }
        for (int ct = 0; ct < ECH / 16; ++ct) {
            const unsigned short* p = ebq + ct * 16 * SZEB;
            s16x8 B0 = *(const s16x8*)p;
            s16x8 B1 = *(const s16x8*)(p + 32);
            f32x4 acc = {0.f, 0.f, 0.f, 0.f};
            acc = __builtin_amdgcn_mfma_f32_16x16x32_bf16(A0, B0, acc, 0, 0, 0);
            acc = __builtin_amdgcn_mfma_f32_16x16x32_bf16(A1, B1, acc, 0, 0, 0);
            float en = enl[ct * 16 + n15];
#pragma unroll
            for (int r = 0; r < 4; ++r) {
                float d = fmaf(-2.f, acc[r], en);
                if (d <= thr[r]) {
                    int t = w * 16 + 4 * q + r;
                    int pos = atomicAdd(&ccnt[t], 1);
                    if (pos < CAP) cand[t][pos] = ch * ECH + ct * 16 + n15;
                }
            }
        }
    }
    __syncthreads();

    // ---- exact fp32 rescore of candidates (frozen arithmetic; global enorm,
    //      R11-verified identical values) ----
    if (tid < MTOK) {
        int t = tid;
        const float* zrow = &zl[t * SZZ];
        int cnt = ccnt[t];
        float best = 3.4e38f;
        int bi = 0;
        if (cnt <= CAP) {
            for (int j = 0; j < cnt; ++j) {
                int c = cand[t][j];
                float d = exact_dist(zrow, emb, enorm, c);
                if (d < best || (d == best && c < bi)) { best = d; bi = c; }
            }
        } else {   // overflow fallback (rare at CAP=16): exact scan, ascending
            for (int c = 0; c < KC; ++c) {
                float d = exact_dist(zrow, emb, enorm, c);
                if (d < best) { best = d; bi = c; }
            }
        }
        fi[t] = bi;
        out[OFF_IDX + t0 + t] = (float)bi;   // coalesced
        atomicAdd(&hist[bi], 1);
    }
    __syncthreads();

    // ---- z_q epilogue: z + (e[code] - z), coalesced per channel ----
#pragma unroll
    for (int j = 0; j < 16; ++j) {
        int idx = tid + j * 256;   // 0..4095
        int c = idx >> 6;
        int t = idx & 63;
        int code = fi[t];
        float ev = emb[(size_t)code * CH + c];   // L1/L2-hot gather
        float zv = zl[t * SZZ + c];
        out[OFF_ZQ + ((size_t)bb * CH + c) * SP + s0 + t] = zv + (ev - zv);
    }

    // ---- z statistics at kernel tail (zs aliased onto dead cand, R11) ----
    {
        float* zs1 = reinterpret_cast<float*>(cand);   // 2048 B needed <= 4096 B
        float* zs2 = zs1 + 256;
        int c = tid >> 2, qq = tid & 3;
        float s1 = 0.f, s2 = 0.f;
        for (int tt = 0; tt < 16; ++tt) {
            float v = zl[(qq * 16 + tt) * SZZ + c];
            s1 += v;
            s2 = fmaf(v, v, s2);
        }
        zs1[tid] = s1;
        zs2[tid] = s2;
        __syncthreads();
        if (tid < 64) {
            float a = zs1[4 * tid] + zs1[4 * tid + 1] + zs1[4 * tid + 2] + zs1[4 * tid + 3];
            atomicAdd(&sum_zc[tid], a);
            float bsum = zs2[4 * tid] + zs2[4 * tid + 1] + zs2[4 * tid + 2] + zs2[4 * tid + 3];
            for (int off = 32; off; off >>= 1) bsum += __shfl_down(bsum, off);
            if (tid == 0) atomicAdd(&sums[0], bsum);
        }
    }
}

__global__ __launch_bounds__(1024) void finalize(const int* __restrict__ hist,
                                                 const float* __restrict__ sums,
                                                 const float* __restrict__ sum_zc,
                                                 const float* __restrict__ sum_ec,
                                                 float* __restrict__ out) {
    __shared__ float red[1024];
    int k = threadIdx.x;
    float p = (float)hist[k] * (1.0f / (float)NTOK);
    red[k] = p * logf(p + 1e-10f);
    __syncthreads();
    for (int off = 512; off; off >>= 1) {
        if (k < off) red[k] += red[k + off];
        __syncthreads();
    }
    if (k == 0) {
        out[OFF_PERP] = expf(-red[0]);
        out[OFF_LOSS] = 0.f;
        double dot = 0.0;
        for (int c = 0; c < CH; ++c) dot += (double)sum_zc[c] * (double)sum_ec[c];
        double mean = ((double)KC * (double)sums[0] + (double)NTOK * (double)sums[1] - 2.0 * dot)
                      / ((double)NTOK * (double)KC);
        out[OFF_MEAN] = (float)mean;
    }
}

extern "C" void kernel_launch(void* const* d_in, const int* in_sizes, int n_in,
                              void* d_out, int out_size, void* d_ws, size_t ws_size,
                              hipStream_t stream) {
    const float* z   = (const float*)d_in[0];
    const float* emb = (const float*)d_in[1];
    float* out = (float*)d_out;

    int*            hist   = (int*)d_ws;
    float*          sums   = (float*)d_ws + 1024;   // [0]=sum_z2 [1]=sum_e2
    float*          sum_zc = (float*)d_ws + 1026;
    float*          sum_ec = (float*)d_ws + 1090;
    float*          enorm  = (float*)d_ws + 1154;
    unsigned short* eb     = (unsigned short*)((int*)d_ws + 4096);  // 128 KB bf16 table

    prep<<<13, 256, 0, stream>>>(emb, hist, sums, sum_zc, sum_ec, enorm, eb);
    vq_main<<<NTOK / MTOK, 256, 0, stream>>>(z, emb, eb, enorm, out, hist, sums, sum_zc);
    finalize<<<1, 1024, 0, stream>>>(hist, sums, sum_zc, sum_ec, out);
}

// Round 13
// 210.063 us; speedup vs baseline: 2.7929x; 1.0072x over previous
//
#include <hip/hip_runtime.h>

// Problem constants (z: [4, 64, 32, 32, 32] f32, embedding: [1024, 64] f32)
#define CH     64
#define KC     1024
#define SP     32768              // 32*32*32
#define NBATCH 4
#define NTOK   (NBATCH * SP)      // 131072
#define MTOK   64                 // tokens per block (R8/R12-verified; beats MTOK=128 via residency)
#define SZZ    68                 // zl row stride (floats)
#define ECH    128                // codes per LDS chunk (8 chunks, R8/R12-verified)
#define NCHK   (KC / ECH)         // 8
#define CAP    16                 // MUST be 16: margin sets are often 9..16 codes; CAP<=8
                                  // routes tokens through the serial full-scan fallback
                                  // (+~400 us chip-wide — R10/R11 A/B proof)
#define MARGIN 3.0f               // > 2*eps, eps = max |d_bf16 - d_fp32| (~0.9)

// d_out flat layout (all float32): z_q, loss, perplexity, indices, mean(dist)
#define OFF_ZQ   0
#define OFF_LOSS (NBATCH * CH * SP)      // 8388608
#define OFF_PERP (OFF_LOSS + 1)
#define OFF_IDX  (OFF_PERP + 1)          // 8388610
#define OFF_MEAN (OFF_IDX + NTOK)        // 8519682

// workspace layout (32-bit words)
// [0,1024)      int   hist
// [1024]        float sum_z2
// [1025]        float sum_e2
// [1026,1090)   float sum_zc[64]
// [1090,1154)   float sum_ec[64]
// [1154,2178)   float enorm[1024]
// [4096,20480)  ushort eb[1024*64]  (bf16 embedding table, 128 KB)

typedef __attribute__((ext_vector_type(8))) short  s16x8;   // 8 bf16 (4 VGPRs)
typedef __attribute__((ext_vector_type(4))) float  f32x4;

__device__ __forceinline__ unsigned short f2bf(float f) {   // RNE, deterministic
    unsigned int u = __float_as_uint(f);
    return (unsigned short)((u + 0x7fffu + ((u >> 16) & 1u)) >> 16);
}

// frozen exact fp32 distance (bitwise identical to round 0: stride-4
// fmaf chains ascending j, combine nrm - 2*((a0+a1)+(a2+a3)))
__device__ __forceinline__ float exact_dist(const float* zrow,
                                            const float* __restrict__ emb,
                                            const float* __restrict__ enl, int c) {
    const float4* er = (const float4*)(emb + (size_t)c * CH);
    float a0 = 0.f, a1 = 0.f, a2 = 0.f, a3 = 0.f;
#pragma unroll
    for (int j = 0; j < 16; ++j) {
        float4 e4 = er[j];
        a0 = fmaf(zrow[4 * j + 0], e4.x, a0);
        a1 = fmaf(zrow[4 * j + 1], e4.y, a1);
        a2 = fmaf(zrow[4 * j + 2], e4.z, a2);
        a3 = fmaf(zrow[4 * j + 3], e4.w, a3);
    }
    return enl[c] - 2.f * ((a0 + a1) + (a2 + a3));
}

// prep: blocks 0-3 enorm, block 4 col-stats + zero sums, 5-8 zero hist,
// 9-12 fp32->bf16 embedding table. (unchanged)
__global__ __launch_bounds__(256) void prep(const float* __restrict__ e,
                                            int* __restrict__ hist,
                                            float* __restrict__ sums,
                                            float* __restrict__ sum_zc,
                                            float* __restrict__ sum_ec,
                                            float* __restrict__ enorm,
                                            unsigned short* __restrict__ eb) {
    const int tid = threadIdx.x;
    const int bk = blockIdx.x;
    if (bk < 4) {
        int k = bk * 256 + tid;
        const float4* row = (const float4*)(e + (size_t)k * CH);
        float n = 0.f;
#pragma unroll
        for (int j = 0; j < CH / 4; ++j) {
            float4 v = row[j];
            n += v.x * v.x + v.y * v.y + v.z * v.z + v.w * v.w;
        }
        enorm[k] = n;
    } else if (bk == 4) {
        if (tid == 0) sums[0] = 0.f;
        if (tid < 64) sum_zc[tid] = 0.f;
        __shared__ float ls1[256];
        __shared__ float r2[4];
        int c = tid & 63;
        int strip = tid >> 6;
        float s1 = 0.f, s2 = 0.f;
        for (int k = strip * 256; k < strip * 256 + 256; ++k) {
            float v = e[k * CH + c];
            s1 += v;
            s2 = fmaf(v, v, s2);
        }
        ls1[tid] = s1;
        for (int off = 32; off; off >>= 1) s2 += __shfl_down(s2, off);
        if ((tid & 63) == 0) r2[tid >> 6] = s2;
        __syncthreads();
        if (strip == 0) sum_ec[c] = ls1[c] + ls1[64 + c] + ls1[128 + c] + ls1[192 + c];
        if (tid == 0) sums[1] = r2[0] + r2[1] + r2[2] + r2[3];
    } else if (bk < 9) {
        hist[(bk - 5) * 256 + tid] = 0;
    } else {
        int base = (bk - 9) * 16384;
        for (int j = 0; j < 64; ++j) {
            int i = base + tid + j * 256;
            eb[i] = f2bf(e[i]);
        }
    }
}

// async global->LDS, 16 B per lane, linear wave dest (base + lane*16). R4-verified.
#define GLD16(gsrc, ldst)                                                        \
    __builtin_amdgcn_global_load_lds(                                            \
        (const __attribute__((address_space(1))) unsigned int*)(gsrc),           \
        (__attribute__((address_space(3))) unsigned int*)(ldst), 16, 0, 0)

// main: R12 kernel (141 us anchor) + two independent verified changes:
//  1) ebl staged via global_load_lds (R4-verified machinery, absmax 0 there):
//     linear 64-short rows, pre-swizzled source granule (l&7)^(l>>3),
//     swizzled reads gsw=q^(n15&7). No reg round-trip, no ds_writes.
//  2) 4x-parallel rescore: candidates strided over 4 threads/token, identical
//     per-candidate exact_dist, lexicographic (d,c) reduce -> same result.
// LDS = 40960 B exactly -> 4 blocks/CU. All value arithmetic frozen.
__global__ __launch_bounds__(256, 2) void vq_main(const float* __restrict__ z,
                                                  const float* __restrict__ emb,
                                                  const unsigned short* __restrict__ eb,
                                                  const float* __restrict__ enorm,
                                                  float* __restrict__ out,
                                                  int* __restrict__ hist,
                                                  float* __restrict__ sums,
                                                  float* __restrict__ sum_zc) {
    __shared__ float zl[MTOK * SZZ];                        // 17408 B fp32 z, token-major
    __shared__ __align__(16) unsigned short ebl[ECH * 64];  // 16384 B bf16 chunk, swizzled
    __shared__ float enl[ECH];                              // 512 B enorm chunk
    __shared__ int   cand[MTOK][CAP];                       // 4096 B (zs-aliased at tail)
    __shared__ int   ccnt[MTOK];                            // 256 B
    __shared__ int   fi[MTOK];                              // 256 B
    __shared__ float rbest[4][MTOK];                        // 1024 B rescore partials
    __shared__ int   rbi[4][MTOK];                          // 1024 B

    const int tid = threadIdx.x;
    const int w = tid >> 6;             // wave 0..3
    const int lane = tid & 63;
    const int n15 = lane & 15;
    const int q = lane >> 4;            // 0..3
    const int t0 = blockIdx.x * MTOK;   // grid = 2048
    const int bb = t0 >> 15;
    const int s0 = t0 & (SP - 1);

    // ---- GLD staging: wave w covers ebl rows [w*32, w*32+32), 4 windows of
    //      1 KB (8 rows). Lane l -> dest granule lane (linear); source row
    //      +(l>>3), source granule (l&7)^(l>>3) (pre-swizzle; row&7 == l>>3).
    //      Reads undo it with gsw = q^(n15&7).  (rule #21 both-sides; R4) ----
    const int l3 = lane >> 3, l7 = lane & 7;
    const size_t gofs = (size_t)((l7 ^ l3) << 3);           // shorts
#define STAGE(cb)                                                             \
    {                                                                         \
        _Pragma("unroll")                                                     \
        for (int it = 0; it < 4; ++it) {                                      \
            const unsigned short* gs =                                        \
                eb + (size_t)((cb) + (w << 5) + it * 8 + l3) * CH + gofs;     \
            GLD16(gs, (char*)ebl + (w << 12) + (it << 10));                   \
        }                                                                     \
    }

    // ---- stage z tile token-major + ccnt (R12 prologue) ----
    {
        const float* zbase = z + ((size_t)bb * CH) * SP + s0;
#pragma unroll
        for (int j = 0; j < 4; ++j) {
            int idx = tid + j * 256;        // 0..1023
            int c = idx >> 4;
            int tq = idx & 15;
            float4 v = *(const float4*)(zbase + (size_t)c * SP + tq * 4);
            zl[(4 * tq + 0) * SZZ + c] = v.x;
            zl[(4 * tq + 1) * SZZ + c] = v.y;
            zl[(4 * tq + 2) * SZZ + c] = v.z;
            zl[(4 * tq + 3) * SZZ + c] = v.w;
        }
        if (tid < MTOK) ccnt[tid] = 0;
    }
    __syncthreads();

    // ---- build persistent A fragments (R8/R12 layout, verified) ----
    s16x8 A0, A1;
    {
        const float* zrow = &zl[(w * 16 + n15) * SZZ];
        float4 za = *(const float4*)(zrow + q * 8);
        float4 zb = *(const float4*)(zrow + q * 8 + 4);
        float4 zc = *(const float4*)(zrow + 32 + q * 8);
        float4 zd = *(const float4*)(zrow + 32 + q * 8 + 4);
        A0[0] = (short)f2bf(za.x); A0[1] = (short)f2bf(za.y);
        A0[2] = (short)f2bf(za.z); A0[3] = (short)f2bf(za.w);
        A0[4] = (short)f2bf(zb.x); A0[5] = (short)f2bf(zb.y);
        A0[6] = (short)f2bf(zb.z); A0[7] = (short)f2bf(zb.w);
        A1[0] = (short)f2bf(zc.x); A1[1] = (short)f2bf(zc.y);
        A1[2] = (short)f2bf(zc.z); A1[3] = (short)f2bf(zc.w);
        A1[4] = (short)f2bf(zd.x); A1[5] = (short)f2bf(zd.y);
        A1[6] = (short)f2bf(zd.z); A1[7] = (short)f2bf(zd.w);
    }
    const int gsw = q ^ (n15 & 7);     // swizzled read granule (row&7 == n15&7)

    // ---- pass 1: per-token min of d_bf (values only), chunked B in LDS ----
    float bmin[4] = {3.4e38f, 3.4e38f, 3.4e38f, 3.4e38f};
    for (int ch = 0; ch < NCHK; ++ch) {
        __syncthreads();   // prior chunk's ebl/enl reads done
        STAGE(ch * ECH)    // async DMA; drained by the next barrier's vmcnt(0)
        if (tid < ECH) enl[tid] = enorm[ch * ECH + tid];
        __syncthreads();
        for (int ct = 0; ct < ECH / 16; ++ct) {
            const s16x8* rowp = (const s16x8*)&ebl[(size_t)(ct * 16 + n15) << 6];
            s16x8 B0 = rowp[gsw];
            s16x8 B1 = rowp[gsw ^ 4];
            f32x4 acc = {0.f, 0.f, 0.f, 0.f};
            acc = __builtin_amdgcn_mfma_f32_16x16x32_bf16(A0, B0, acc, 0, 0, 0);
            acc = __builtin_amdgcn_mfma_f32_16x16x32_bf16(A1, B1, acc, 0, 0, 0);
            float en = enl[ct * 16 + n15];
#pragma unroll
            for (int r = 0; r < 4; ++r) {
                float d = fmaf(-2.f, acc[r], en);
                bmin[r] = fminf(bmin[r], d);
            }
        }
    }
    // butterfly over n15: min lands in all 16 lanes (R12-verified) ->
    // threshold wave-local, no dmin_l, no extra barrier
#pragma unroll
    for (int off = 1; off < 16; off <<= 1)
#pragma unroll
        for (int r = 0; r < 4; ++r)
            bmin[r] = fminf(bmin[r], __shfl_xor(bmin[r], off));
    float thr[4];
#pragma unroll
    for (int r = 0; r < 4; ++r) thr[r] = bmin[r] + MARGIN;

    // ---- pass 2: identical compute, collect candidates within margin.
    //      chunk order 7,0..6: chunk 7 (ebl+enl) still resident -> no restage ----
    for (int cc = 0; cc < NCHK; ++cc) {
        int ch = (cc == 0) ? (NCHK - 1) : (cc - 1);
        if (cc) {
            __syncthreads();
            STAGE(ch * ECH)
            if (tid < ECH) enl[tid] = enorm[ch * ECH + tid];
            __syncthreads();
        }
        for (int ct = 0; ct < ECH / 16; ++ct) {
            const s16x8* rowp = (const s16x8*)&ebl[(size_t)(ct * 16 + n15) << 6];
            s16x8 B0 = rowp[gsw];
            s16x8 B1 = rowp[gsw ^ 4];
            f32x4 acc = {0.f, 0.f, 0.f, 0.f};
            acc = __builtin_amdgcn_mfma_f32_16x16x32_bf16(A0, B0, acc, 0, 0, 0);
            acc = __builtin_amdgcn_mfma_f32_16x16x32_bf16(A1, B1, acc, 0, 0, 0);
            float en = enl[ct * 16 + n15];
#pragma unroll
            for (int r = 0; r < 4; ++r) {
                float d = fmaf(-2.f, acc[r], en);
                if (d <= thr[r]) {
                    int t = w * 16 + 4 * q + r;
                    int pos = atomicAdd(&ccnt[t], 1);
                    if (pos < CAP) cand[t][pos] = ch * ECH + ct * 16 + n15;
                }
            }
        }
    }
    __syncthreads();

    // ---- exact fp32 rescore, 4x-parallel: token t = tid&63, part = tid>>6
    //      takes candidates j = part, part+4, ... Per-candidate arithmetic is
    //      byte-identical; lexicographic (d,c) min over the set is evaluation-
    //      order-independent -> result identical to the serial loop. ----
    {
        const int t = tid & 63;
        const int part = tid >> 6;
        const float* zrow = &zl[t * SZZ];
        int cnt = ccnt[t];
        float best = 3.4e38f;
        int bi = 0;
        if (cnt <= CAP) {
            for (int j = part; j < cnt; j += 4) {
                int c = cand[t][j];
                float d = exact_dist(zrow, emb, enorm, c);
                if (d < best || (d == best && c < bi)) { best = d; bi = c; }
            }
        } else {   // overflow fallback (rare at CAP=16): strided exact scan
            for (int c = part; c < KC; c += 4) {
                float d = exact_dist(zrow, emb, enorm, c);
                if (d < best || (d == best && c < bi)) { best = d; bi = c; }
            }
        }
        rbest[part][t] = best;
        rbi[part][t] = bi;
    }
    __syncthreads();
    if (tid < MTOK) {
        float best = rbest[0][tid];
        int bi = rbi[0][tid];
#pragma unroll
        for (int p = 1; p < 4; ++p) {
            float b = rbest[p][tid];
            int i = rbi[p][tid];
            if (b < best || (b == best && i < bi)) { best = b; bi = i; }
        }
        fi[tid] = bi;
        out[OFF_IDX + t0 + tid] = (float)bi;   // coalesced
        atomicAdd(&hist[bi], 1);
    }
    __syncthreads();

    // ---- z_q epilogue: z + (e[code] - z), coalesced per channel ----
#pragma unroll
    for (int j = 0; j < 16; ++j) {
        int idx = tid + j * 256;   // 0..4095
        int c = idx >> 6;
        int t = idx & 63;
        int code = fi[t];
        float ev = emb[(size_t)code * CH + c];   // L1/L2-hot gather
        float zv = zl[t * SZZ + c];
        out[OFF_ZQ + ((size_t)bb * CH + c) * SP + s0 + t] = zv + (ev - zv);
    }

    // ---- z statistics at kernel tail (zs aliased onto dead cand, R12) ----
    {
        float* zs1 = reinterpret_cast<float*>(cand);   // 2048 B needed <= 4096 B
        float* zs2 = zs1 + 256;
        int c = tid >> 2, qq = tid & 3;
        float s1 = 0.f, s2 = 0.f;
        for (int tt = 0; tt < 16; ++tt) {
            float v = zl[(qq * 16 + tt) * SZZ + c];
            s1 += v;
            s2 = fmaf(v, v, s2);
        }
        zs1[tid] = s1;
        zs2[tid] = s2;
        __syncthreads();
        if (tid < 64) {
            float a = zs1[4 * tid] + zs1[4 * tid + 1] + zs1[4 * tid + 2] + zs1[4 * tid + 3];
            atomicAdd(&sum_zc[tid], a);
            float bsum = zs2[4 * tid] + zs2[4 * tid + 1] + zs2[4 * tid + 2] + zs2[4 * tid + 3];
            for (int off = 32; off; off >>= 1) bsum += __shfl_down(bsum, off);
            if (tid == 0) atomicAdd(&sums[0], bsum);
        }
    }
#undef STAGE
}

__global__ __launch_bounds__(1024) void finalize(const int* __restrict__ hist,
                                                 const float* __restrict__ sums,
                                                 const float* __restrict__ sum_zc,
                                                 const float* __restrict__ sum_ec,
                                                 float* __restrict__ out) {
    __shared__ float red[1024];
    int k = threadIdx.x;
    float p = (float)hist[k] * (1.0f / (float)NTOK);
    red[k] = p * logf(p + 1e-10f);
    __syncthreads();
    for (int off = 512; off; off >>= 1) {
        if (k < off) red[k] += red[k + off];
        __syncthreads();
    }
    if (k == 0) {
        out[OFF_PERP] = expf(-red[0]);
        out[OFF_LOSS] = 0.f;
        double dot = 0.0;
        for (int c = 0; c < CH; ++c) dot += (double)sum_zc[c] * (double)sum_ec[c];
        double mean = ((double)KC * (double)sums[0] + (double)NTOK * (double)sums[1] - 2.0 * dot)
                      / ((double)NTOK * (double)KC);
        out[OFF_MEAN] = (float)mean;
    }
}

extern "C" void kernel_launch(void* const* d_in, const int* in_sizes, int n_in,
                              void* d_out, int out_size, void* d_ws, size_t ws_size,
                              hipStream_t stream) {
    const float* z   = (const float*)d_in[0];
    const float* emb = (const float*)d_in[1];
    float* out = (float*)d_out;

    int*            hist   = (int*)d_ws;
    float*          sums   = (float*)d_ws + 1024;   // [0]=sum_z2 [1]=sum_e2
    float*          sum_zc = (float*)d_ws + 1026;
    float*          sum_ec = (float*)d_ws + 1090;
    float*          enorm  = (float*)d_ws + 1154;
    unsigned short* eb     = (unsigned short*)((int*)d_ws + 4096);  // 128 KB bf16 table

    prep<<<13, 256, 0, stream>>>(emb, hist, sums, sum_zc, sum_ec, enorm, eb);
    vq_main<<<NTOK / MTOK, 256, 0, stream>>>(z, emb, eb, enorm, out, hist, sums, sum_zc);
    finalize<<<1, 1024, 0, stream>>>(hist, sums, sum_zc, sum_ec, out);
}